// Round 1
// baseline (150.758 us; speedup 1.0000x reference)
//
#include <hip/hip_runtime.h>
#include <math.h>

// RUL loss: out = theta * sum(score(diff)) + (1-theta) * sqrt(mean(diff^2))
// score(d) = (d<0 ? exp(-d/13) : exp(d/10)) - 1
// N = 16777216 fp32 elements per input. Memory-bound: 128 MB read.

#define RUL_N 16777216
#define PART_BLOCKS 2048
#define BLOCK_THREADS 256

__global__ __launch_bounds__(BLOCK_THREADS) void rul_partial_kernel(
    const float* __restrict__ pred,
    const float* __restrict__ tru,
    float* __restrict__ partials /* [2 * PART_BLOCKS] */) {
    const float4* __restrict__ p4 = (const float4*)pred;
    const float4* __restrict__ t4 = (const float4*)tru;
    const int n4 = RUL_N / 4;

    float s_score = 0.0f;
    float s_sq = 0.0f;

    const int stride = gridDim.x * blockDim.x;
    for (int i = blockIdx.x * blockDim.x + threadIdx.x; i < n4; i += stride) {
        float4 p = p4[i];
        float4 t = t4[i];
        float d0 = p.x - t.x;
        float d1 = p.y - t.y;
        float d2 = p.z - t.z;
        float d3 = p.w - t.w;

        // branchless piecewise exp: slope = d<0 ? -1/13 : 1/10
        float e0 = __expf(d0 * (d0 < 0.0f ? (-1.0f / 13.0f) : (1.0f / 10.0f)));
        float e1 = __expf(d1 * (d1 < 0.0f ? (-1.0f / 13.0f) : (1.0f / 10.0f)));
        float e2 = __expf(d2 * (d2 < 0.0f ? (-1.0f / 13.0f) : (1.0f / 10.0f)));
        float e3 = __expf(d3 * (d3 < 0.0f ? (-1.0f / 13.0f) : (1.0f / 10.0f)));

        s_score += (e0 - 1.0f) + (e1 - 1.0f) + (e2 - 1.0f) + (e3 - 1.0f);
        s_sq += d0 * d0 + d1 * d1 + d2 * d2 + d3 * d3;
    }

    // wave-64 butterfly reduce
    #pragma unroll
    for (int off = 32; off > 0; off >>= 1) {
        s_score += __shfl_down(s_score, off);
        s_sq += __shfl_down(s_sq, off);
    }

    __shared__ float sm_score[BLOCK_THREADS / 64];
    __shared__ float sm_sq[BLOCK_THREADS / 64];
    const int wave = threadIdx.x >> 6;
    const int lane = threadIdx.x & 63;
    if (lane == 0) {
        sm_score[wave] = s_score;
        sm_sq[wave] = s_sq;
    }
    __syncthreads();
    if (threadIdx.x == 0) {
        float a = 0.0f, b = 0.0f;
        #pragma unroll
        for (int w = 0; w < BLOCK_THREADS / 64; ++w) {
            a += sm_score[w];
            b += sm_sq[w];
        }
        partials[blockIdx.x] = a;
        partials[PART_BLOCKS + blockIdx.x] = b;
    }
}

__global__ __launch_bounds__(BLOCK_THREADS) void rul_finalize_kernel(
    const float* __restrict__ partials,
    const float* __restrict__ theta_ptr,
    float* __restrict__ out) {
    float a = 0.0f, b = 0.0f;
    for (int i = threadIdx.x; i < PART_BLOCKS; i += BLOCK_THREADS) {
        a += partials[i];
        b += partials[PART_BLOCKS + i];
    }
    #pragma unroll
    for (int off = 32; off > 0; off >>= 1) {
        a += __shfl_down(a, off);
        b += __shfl_down(b, off);
    }
    __shared__ float sm_a[BLOCK_THREADS / 64];
    __shared__ float sm_b[BLOCK_THREADS / 64];
    const int wave = threadIdx.x >> 6;
    const int lane = threadIdx.x & 63;
    if (lane == 0) {
        sm_a[wave] = a;
        sm_b[wave] = b;
    }
    __syncthreads();
    if (threadIdx.x == 0) {
        float sa = 0.0f, sb = 0.0f;
        #pragma unroll
        for (int w = 0; w < BLOCK_THREADS / 64; ++w) {
            sa += sm_a[w];
            sb += sm_b[w];
        }
        float theta = theta_ptr[0];
        float rmse = sqrtf(sb * (1.0f / (float)RUL_N));
        out[0] = theta * sa + (1.0f - theta) * rmse;
    }
}

extern "C" void kernel_launch(void* const* d_in, const int* in_sizes, int n_in,
                              void* d_out, int out_size, void* d_ws, size_t ws_size,
                              hipStream_t stream) {
    const float* pred = (const float*)d_in[0];
    const float* tru = (const float*)d_in[1];
    const float* theta = (const float*)d_in[2];
    float* out = (float*)d_out;
    float* partials = (float*)d_ws; // needs 2 * PART_BLOCKS * 4 = 16 KB

    rul_partial_kernel<<<PART_BLOCKS, BLOCK_THREADS, 0, stream>>>(pred, tru, partials);
    rul_finalize_kernel<<<1, BLOCK_THREADS, 0, stream>>>(partials, theta, out);
}

// Round 2
// 149.178 us; speedup vs baseline: 1.0106x; 1.0106x over previous
//
#include <hip/hip_runtime.h>
#include <math.h>

// RUL loss: out = theta * sum(score(diff)) + (1-theta) * sqrt(mean(diff^2))
// score(d) = (d<0 ? exp(-d/13) : exp(d/10)) - 1
// N = 16777216 fp32 elements per input. Memory-bound: 128 MB read.
//
// R1: compile-time trip count + two-phase (load-all / compute-all) so the
// compiler issues all 16 global_load_dwordx4 before the first waitcnt.
// R0 was latency-bound at 3.0 TB/s (2 loads in flight per wave).

#define RUL_N 16777216
#define PART_BLOCKS 2048
#define BLOCK_THREADS 256
#define GRID_THREADS (PART_BLOCKS * BLOCK_THREADS)
#define ITERS ((RUL_N / 4) / GRID_THREADS)   // = 8, compile-time constant

__global__ __launch_bounds__(BLOCK_THREADS) void rul_partial_kernel(
    const float* __restrict__ pred,
    const float* __restrict__ tru,
    float* __restrict__ partials /* [2 * PART_BLOCKS] */) {
    const float4* __restrict__ p4 = (const float4*)pred;
    const float4* __restrict__ t4 = (const float4*)tru;

    const int tid = blockIdx.x * BLOCK_THREADS + threadIdx.x;

    // Phase 1: issue ALL loads (16 x dwordx4 in flight per lane).
    float4 p[ITERS];
    float4 t[ITERS];
#pragma unroll
    for (int k = 0; k < ITERS; ++k) {
        p[k] = p4[tid + k * GRID_THREADS];
        t[k] = t4[tid + k * GRID_THREADS];
    }

    // Phase 2: compute. Two accumulator pairs to shorten dependency chains.
    float s_score0 = 0.0f, s_score1 = 0.0f;
    float s_sq0 = 0.0f, s_sq1 = 0.0f;
#pragma unroll
    for (int k = 0; k < ITERS; ++k) {
        float d0 = p[k].x - t[k].x;
        float d1 = p[k].y - t[k].y;
        float d2 = p[k].z - t[k].z;
        float d3 = p[k].w - t[k].w;

        float e0 = __expf(d0 * (d0 < 0.0f ? (-1.0f / 13.0f) : (1.0f / 10.0f)));
        float e1 = __expf(d1 * (d1 < 0.0f ? (-1.0f / 13.0f) : (1.0f / 10.0f)));
        float e2 = __expf(d2 * (d2 < 0.0f ? (-1.0f / 13.0f) : (1.0f / 10.0f)));
        float e3 = __expf(d3 * (d3 < 0.0f ? (-1.0f / 13.0f) : (1.0f / 10.0f)));

        s_score0 += (e0 - 1.0f) + (e1 - 1.0f);
        s_score1 += (e2 - 1.0f) + (e3 - 1.0f);
        s_sq0 += d0 * d0 + d1 * d1;
        s_sq1 += d2 * d2 + d3 * d3;
    }
    float s_score = s_score0 + s_score1;
    float s_sq = s_sq0 + s_sq1;

    // wave-64 reduce
#pragma unroll
    for (int off = 32; off > 0; off >>= 1) {
        s_score += __shfl_down(s_score, off);
        s_sq += __shfl_down(s_sq, off);
    }

    __shared__ float sm_score[BLOCK_THREADS / 64];
    __shared__ float sm_sq[BLOCK_THREADS / 64];
    const int wave = threadIdx.x >> 6;
    const int lane = threadIdx.x & 63;
    if (lane == 0) {
        sm_score[wave] = s_score;
        sm_sq[wave] = s_sq;
    }
    __syncthreads();
    if (threadIdx.x == 0) {
        float a = 0.0f, b = 0.0f;
#pragma unroll
        for (int w = 0; w < BLOCK_THREADS / 64; ++w) {
            a += sm_score[w];
            b += sm_sq[w];
        }
        partials[blockIdx.x] = a;
        partials[PART_BLOCKS + blockIdx.x] = b;
    }
}

__global__ __launch_bounds__(BLOCK_THREADS) void rul_finalize_kernel(
    const float* __restrict__ partials,
    const float* __restrict__ theta_ptr,
    float* __restrict__ out) {
    float a = 0.0f, b = 0.0f;
#pragma unroll
    for (int i = threadIdx.x; i < PART_BLOCKS; i += BLOCK_THREADS) {
        a += partials[i];
        b += partials[PART_BLOCKS + i];
    }
#pragma unroll
    for (int off = 32; off > 0; off >>= 1) {
        a += __shfl_down(a, off);
        b += __shfl_down(b, off);
    }
    __shared__ float sm_a[BLOCK_THREADS / 64];
    __shared__ float sm_b[BLOCK_THREADS / 64];
    const int wave = threadIdx.x >> 6;
    const int lane = threadIdx.x & 63;
    if (lane == 0) {
        sm_a[wave] = a;
        sm_b[wave] = b;
    }
    __syncthreads();
    if (threadIdx.x == 0) {
        float sa = 0.0f, sb = 0.0f;
#pragma unroll
        for (int w = 0; w < BLOCK_THREADS / 64; ++w) {
            sa += sm_a[w];
            sb += sm_b[w];
        }
        float theta = theta_ptr[0];
        float rmse = sqrtf(sb * (1.0f / (float)RUL_N));
        out[0] = theta * sa + (1.0f - theta) * rmse;
    }
}

extern "C" void kernel_launch(void* const* d_in, const int* in_sizes, int n_in,
                              void* d_out, int out_size, void* d_ws, size_t ws_size,
                              hipStream_t stream) {
    const float* pred = (const float*)d_in[0];
    const float* tru = (const float*)d_in[1];
    const float* theta = (const float*)d_in[2];
    float* out = (float*)d_out;
    float* partials = (float*)d_ws; // needs 2 * PART_BLOCKS * 4 = 16 KB

    rul_partial_kernel<<<PART_BLOCKS, BLOCK_THREADS, 0, stream>>>(pred, tru, partials);
    rul_finalize_kernel<<<1, BLOCK_THREADS, 0, stream>>>(partials, theta, out);
}

// Round 3
// 147.545 us; speedup vs baseline: 1.0218x; 1.0111x over previous
//
#include <hip/hip_runtime.h>
#include <math.h>

// RUL loss: out = theta * sum(score(diff)) + (1-theta) * sqrt(mean(diff^2))
// score(d) = (d<0 ? exp(-d/13) : exp(d/10)) - 1
// N = 16777216 fp32. Memory-bound: 134 MB logical read (half L3-resident).
//
// R2: R1's two-phase load/compute was defeated by the machine scheduler
// (VGPR=28 proved loads were sunk + serialized, ~2 KB/wave in flight).
// Fix: __builtin_amdgcn_sched_barrier(0) fences around the load phase pin
// all 16 global_load_dwordx4 before the first use; __launch_bounds__(256,2)
// raises the VGPR budget so the 16 float4 stay live (16 KB/wave in flight).

#define RUL_N 16777216
#define PART_BLOCKS 2048
#define BLOCK_THREADS 256
#define GRID_THREADS (PART_BLOCKS * BLOCK_THREADS)
#define ITERS ((RUL_N / 4) / GRID_THREADS)   // = 8, compile-time constant

__global__ __launch_bounds__(BLOCK_THREADS, 2) void rul_partial_kernel(
    const float* __restrict__ pred,
    const float* __restrict__ tru,
    float* __restrict__ partials /* [2 * PART_BLOCKS] */) {
    const float4* __restrict__ p4 = (const float4*)pred;
    const float4* __restrict__ t4 = (const float4*)tru;

    const int tid = blockIdx.x * BLOCK_THREADS + threadIdx.x;

    float4 p[ITERS];
    float4 t[ITERS];

    // ---- load phase: all 16 dwordx4 issued before any use ----
    __builtin_amdgcn_sched_barrier(0);
#pragma unroll
    for (int k = 0; k < ITERS; ++k) {
        p[k] = p4[tid + k * GRID_THREADS];
        t[k] = t4[tid + k * GRID_THREADS];
    }
    __builtin_amdgcn_sched_barrier(0);

    // ---- compute phase ----
    float s_score0 = 0.0f, s_score1 = 0.0f;
    float s_sq0 = 0.0f, s_sq1 = 0.0f;
#pragma unroll
    for (int k = 0; k < ITERS; ++k) {
        float d0 = p[k].x - t[k].x;
        float d1 = p[k].y - t[k].y;
        float d2 = p[k].z - t[k].z;
        float d3 = p[k].w - t[k].w;

        float e0 = __expf(d0 * (d0 < 0.0f ? (-1.0f / 13.0f) : (1.0f / 10.0f)));
        float e1 = __expf(d1 * (d1 < 0.0f ? (-1.0f / 13.0f) : (1.0f / 10.0f)));
        float e2 = __expf(d2 * (d2 < 0.0f ? (-1.0f / 13.0f) : (1.0f / 10.0f)));
        float e3 = __expf(d3 * (d3 < 0.0f ? (-1.0f / 13.0f) : (1.0f / 10.0f)));

        s_score0 += (e0 - 1.0f) + (e1 - 1.0f);
        s_score1 += (e2 - 1.0f) + (e3 - 1.0f);
        s_sq0 += d0 * d0 + d1 * d1;
        s_sq1 += d2 * d2 + d3 * d3;
    }
    float s_score = s_score0 + s_score1;
    float s_sq = s_sq0 + s_sq1;

    // wave-64 reduce
#pragma unroll
    for (int off = 32; off > 0; off >>= 1) {
        s_score += __shfl_down(s_score, off);
        s_sq += __shfl_down(s_sq, off);
    }

    __shared__ float sm_score[BLOCK_THREADS / 64];
    __shared__ float sm_sq[BLOCK_THREADS / 64];
    const int wave = threadIdx.x >> 6;
    const int lane = threadIdx.x & 63;
    if (lane == 0) {
        sm_score[wave] = s_score;
        sm_sq[wave] = s_sq;
    }
    __syncthreads();
    if (threadIdx.x == 0) {
        float a = 0.0f, b = 0.0f;
#pragma unroll
        for (int w = 0; w < BLOCK_THREADS / 64; ++w) {
            a += sm_score[w];
            b += sm_sq[w];
        }
        partials[blockIdx.x] = a;
        partials[PART_BLOCKS + blockIdx.x] = b;
    }
}

__global__ __launch_bounds__(BLOCK_THREADS) void rul_finalize_kernel(
    const float* __restrict__ partials,
    const float* __restrict__ theta_ptr,
    float* __restrict__ out) {
    float a = 0.0f, b = 0.0f;
#pragma unroll
    for (int i = threadIdx.x; i < PART_BLOCKS; i += BLOCK_THREADS) {
        a += partials[i];
        b += partials[PART_BLOCKS + i];
    }
#pragma unroll
    for (int off = 32; off > 0; off >>= 1) {
        a += __shfl_down(a, off);
        b += __shfl_down(b, off);
    }
    __shared__ float sm_a[BLOCK_THREADS / 64];
    __shared__ float sm_b[BLOCK_THREADS / 64];
    const int wave = threadIdx.x >> 6;
    const int lane = threadIdx.x & 63;
    if (lane == 0) {
        sm_a[wave] = a;
        sm_b[wave] = b;
    }
    __syncthreads();
    if (threadIdx.x == 0) {
        float sa = 0.0f, sb = 0.0f;
#pragma unroll
        for (int w = 0; w < BLOCK_THREADS / 64; ++w) {
            sa += sm_a[w];
            sb += sm_b[w];
        }
        float theta = theta_ptr[0];
        float rmse = sqrtf(sb * (1.0f / (float)RUL_N));
        out[0] = theta * sa + (1.0f - theta) * rmse;
    }
}

extern "C" void kernel_launch(void* const* d_in, const int* in_sizes, int n_in,
                              void* d_out, int out_size, void* d_ws, size_t ws_size,
                              hipStream_t stream) {
    const float* pred = (const float*)d_in[0];
    const float* tru = (const float*)d_in[1];
    const float* theta = (const float*)d_in[2];
    float* out = (float*)d_out;
    float* partials = (float*)d_ws; // needs 2 * PART_BLOCKS * 4 = 16 KB

    rul_partial_kernel<<<PART_BLOCKS, BLOCK_THREADS, 0, stream>>>(pred, tru, partials);
    rul_finalize_kernel<<<1, BLOCK_THREADS, 0, stream>>>(partials, theta, out);
}